// Round 9
// baseline (317.759 us; speedup 1.0000x reference)
//
#include <hip/hip_runtime.h>
#include <math.h>

typedef __attribute__((ext_vector_type(4))) float f32x4;
typedef __bf16 bf16x8 __attribute__((ext_vector_type(8)));

#define LOG_2PI_F 1.8378770664093453f

// scal layout (ints): [0]=cnt0 [1]=cnt1 [4]=base1 [5]=mact [6]=mpad

__device__ static inline ushort f2bf(float f) {
    union { float f; unsigned u; } c; c.f = f;
    unsigned u = c.u;
    unsigned r = (u + 0x7FFFu + ((u >> 16) & 1u)) >> 16;
    return (ushort)r;
}
__device__ static inline float bf2f(ushort h) {
    union { unsigned u; float f; } c; c.u = ((unsigned)h) << 16;
    return c.f;
}

// ================= fused prep =================
// blocks 0..127: compaction chunk b (redundant-prefix, no inter-block deps)
//   - each wave ballot-counts its 8192-token quarter, overlap with [0, b*256)
//   - chunk-b slot assignment (wave/lane prefix), prey -> out[i]=0
//   - scatter-copy this chunk's obs rows to compacted bf16 obsb (gather fused)
//   - pad/gap obsb rows stay poisoned: GEMM rows are independent, head_final skips gaps
// blocks 128..3359: weight transpose fp32 [R][C] -> bf16 [C][R]
__global__ __launch_bounds__(256) void prep_all(
    const float* __restrict__ obs, const int* __restrict__ role_ids,
    const float* __restrict__ W0, const float* __restrict__ W1,
    const float* __restrict__ W2, const float* __restrict__ hW1,
    const float* __restrict__ hW2,
    ushort* __restrict__ obsb, ushort* __restrict__ W0t, ushort* __restrict__ W1t,
    ushort* __restrict__ W2t, ushort* __restrict__ hW1t, ushort* __restrict__ hW2t,
    int* __restrict__ slot2tok, int* __restrict__ scal, float* __restrict__ out) {
    __shared__ float tile[32][33];
    __shared__ int sh[16];
    __shared__ int s_of[256];
    const int tid = threadIdx.x;
    const int id = blockIdx.x;

    if (id < 128) {
        const int b = id;
        const int lane = tid & 63, w = tid >> 6;
        const int limit = b << 8;  // b*256
        int pre0 = 0, pre1 = 0, tot0 = 0, tot1 = 0;
        for (int g = 0; g < 128; g++) {
            int i = (w << 13) + (g << 6) + lane;
            int r = role_ids[i];
            int c0 = (int)__popcll(__ballot(r == 0));
            int c1 = (int)__popcll(__ballot(r == 1));
            int gs = (w << 13) + (g << 6);
            if (gs < limit) { pre0 += c0; pre1 += c1; }  // group fully before chunk b
            tot0 += c0; tot1 += c1;
        }
        if (lane == 0) { sh[w] = pre0; sh[4 + w] = pre1; sh[8 + w] = tot0; sh[12 + w] = tot1; }
        __syncthreads();
        const int preA0 = sh[0] + sh[1] + sh[2] + sh[3];
        const int preA1 = sh[4] + sh[5] + sh[6] + sh[7];
        const int totA0 = sh[8] + sh[9] + sh[10] + sh[11];
        const int totA1 = sh[12] + sh[13] + sh[14] + sh[15];
        __syncthreads();
        const int base1 = (totA0 + 127) & ~127;
        if (b == 0 && tid == 0) {
            int mact = base1 + totA1;
            scal[0] = totA0; scal[1] = totA1;
            scal[4] = base1; scal[5] = mact; scal[6] = (mact + 127) & ~127;
        }
        // chunk-b assignment
        const int i = (b << 8) + tid;
        const int r = role_ids[i];
        unsigned long long b0 = __ballot(r == 0);
        unsigned long long b1 = __ballot(r == 1);
        if (lane == 0) { sh[w] = (int)__popcll(b0); sh[4 + w] = (int)__popcll(b1); }
        __syncthreads();
        int w0 = 0, w1 = 0;
        for (int j = 0; j < 4; j++) if (j < w) { w0 += sh[j]; w1 += sh[4 + j]; }
        unsigned long long lt = (lane == 0) ? 0ull
                             : ((lane == 63) ? 0x7FFFFFFFFFFFFFFFull : ((1ull << lane) - 1));
        int slot = -1;
        if (r == 0)      slot = preA0 + w0 + (int)__popcll(b0 & lt);
        else if (r == 1) slot = base1 + preA1 + w1 + (int)__popcll(b1 & lt);
        if (slot >= 0) slot2tok[slot] = i;
        else           out[i] = 0.f;          // prey -> logprob 0 (memset fused)
        s_of[tid] = slot;
        __syncthreads();
        // scatter-copy this chunk's obs rows (wave per row)
        for (int rr = w; rr < 256; rr += 4) {
            int s = s_of[rr];
            if (s < 0) continue;
            float2 v = ((const float2*)(obs + (size_t)(limit + rr) * 128))[lane];
            ((ushort2*)(obsb + (size_t)s * 128))[lane] = (ushort2){f2bf(v.x), f2bf(v.y)};
        }
        return;
    }

    // ---- transpose part ----
    int tix = id - 128;
    const float* in; ushort* outp; int R, C, t;
    if (tix < 1024)      { in = W1;             outp = W1t;             R = 1024; C = 1024; t = tix; }
    else if (tix < 2048) { in = W2;             outp = W2t;             R = 1024; C = 1024; t = tix - 1024; }
    else if (tix < 2560) { in = hW1;            outp = hW1t;            R = 1024; C = 512;  t = tix - 2048; }
    else if (tix < 3072) { in = hW1 + 1024*512; outp = hW1t + 512*1024; R = 1024; C = 512;  t = tix - 2560; }
    else if (tix < 3200) { in = W0;             outp = W0t;             R = 128;  C = 1024; t = tix - 3072; }
    else if (tix < 3216) { in = hW2;            outp = hW2t;            R = 512;  C = 8;    t = tix - 3200; }
    else                 { in = hW2 + 512*8;    outp = hW2t + 8*512;    R = 512;  C = 8;    t = tix - 3216; }
    const int tx = tid & 31, ty = tid >> 5;
    int tX = (C + 31) >> 5;
    int c0 = (t % tX) << 5, r0 = (t / tX) << 5;
    for (int j = ty; j < 32; j += 8) {
        int r = r0 + j, c = c0 + tx;
        if (r < R && c < C) tile[j][tx] = in[(size_t)r * C + c];
    }
    __syncthreads();
    for (int j = ty; j < 32; j += 8) {
        int c = c0 + j, r = r0 + tx;
        if (r < R && c < C) outp[(size_t)c * R + r] = f2bf(tile[tx][j]);
    }
}

// ---------------- GEMM: C[M][N] = relu(A[M][K] @ Bt[N][K]^T + bias ...) ----
// 128x256 tile, BK=64, 512 threads = 8 waves (2x4), per-wave 64x64 via 4x4 16x16x32 frags.
// Single-buffer LDS 48KB (3 blocks/CU — round-5 proven), XOR-swizzled (conflicts=0).
// XCD group-swizzle (round-6 proven: FETCH 92->39MB): same-brow col-blocks on one XCD.
// mode 0: plain.  mode 1: L0 (+ per-role W0 row).  mode 2: head1 (role-pure row tiles).
__global__ __launch_bounds__(512, 4) void gemm_bias_relu(
    const ushort* __restrict__ A, const ushort* __restrict__ Bt,
    const float* __restrict__ bias, ushort* __restrict__ C,
    int N, int K, const int* __restrict__ scal,
    const float* __restrict__ rolerows, int mode) {
    const int nb = N >> 8;                 // 256-wide col tiles
    const int xcd = blockIdx.x & 7, slot = blockIdx.x >> 3;
    const int wgid = ((slot / nb) * 8 + xcd) * nb + (slot % nb);
    const int brow = wgid / nb;
    const int bcol = wgid % nb;
    const int base1 = scal[4];
    const int mpad = scal[6];
    if (brow * 128 >= mpad) return;

    if (mode == 2) {
        int rt = (brow * 128 >= base1) ? 1 : 0;
        Bt += (size_t)rt * 512 * 1024;
        bias += rt * 512;
    }

    __shared__ __align__(16) ushort lA[128 * 64];   // 16 KB
    __shared__ __align__(16) ushort lB[256 * 64];   // 32 KB

    const int tid = threadIdx.x;
    const int w = tid >> 6;                // wave 0..7
    const int L = tid & 63;
    const int wr = w >> 2, wc = w & 3;     // 2x4 wave grid
    const int fr = L & 15;
    const int g = L >> 4;                  // k-group 0..3
    const int rsw = (fr & 7) << 4;         // read-side byte XOR
    const int crow4 = g << 2;

    // staging geometry (round-5 verified)
    const int subrow = L >> 3;                       // 0..7 within 8-row chunk
    const int srcofs = ((L & 7) ^ subrow) << 3;      // element offset (inverse swizzle)
    const int aRow = brow * 128 + (w << 4) + subrow; // + 8j
    const int bRow = bcol * 256 + (w << 5) + subrow; // + 8j

    f32x4 acc[4][4];
#pragma unroll
    for (int i = 0; i < 4; i++)
#pragma unroll
        for (int j = 0; j < 4; j++) acc[i][j] = (f32x4){0.f, 0.f, 0.f, 0.f};

    const int nk = K >> 6;
    for (int kt = 0; kt < nk; ++kt) {
        const int k0 = kt << 6;
        const ushort* gA = A + (size_t)aRow * K + k0 + srcofs;
#pragma unroll
        for (int j = 0; j < 2; j++) {
            __builtin_amdgcn_global_load_lds(
                (const __attribute__((address_space(1))) void*)(gA + (size_t)(8 * j) * K),
                (__attribute__((address_space(3))) void*)(&lA[((w << 4) + (j << 3)) << 6]),
                16, 0, 0);
        }
        const ushort* gB = Bt + (size_t)bRow * K + k0 + srcofs;
#pragma unroll
        for (int j = 0; j < 4; j++) {
            __builtin_amdgcn_global_load_lds(
                (const __attribute__((address_space(1))) void*)(gB + (size_t)(8 * j) * K),
                (__attribute__((address_space(3))) void*)(&lB[((w << 5) + (j << 3)) << 6]),
                16, 0, 0);
        }
        __syncthreads();

#pragma unroll
        for (int kk = 0; kk < 2; kk++) {
            const int cbs = ((kk << 6) + (g << 4)) ^ rsw;
            bf16x8 af[4], bfr[4];
#pragma unroll
            for (int m = 0; m < 4; m++)
                af[m] = *(const bf16x8*)((const char*)lA + ((wr << 6) + (m << 4) + fr) * 128 + cbs);
#pragma unroll
            for (int n = 0; n < 4; n++)
                bfr[n] = *(const bf16x8*)((const char*)lB + ((wc << 6) + (n << 4) + fr) * 128 + cbs);
#pragma unroll
            for (int m = 0; m < 4; m++)
#pragma unroll
                for (int n = 0; n < 4; n++)
                    acc[m][n] = __builtin_amdgcn_mfma_f32_16x16x32_bf16(af[m], bfr[n], acc[m][n], 0, 0, 0);
        }
        __syncthreads();
    }

#pragma unroll
    for (int m = 0; m < 4; m++) {
        const int rowb = brow * 128 + (wr << 6) + (m << 4) + crow4;
#pragma unroll
        for (int j = 0; j < 4; j++) {
            const int r = rowb + j;
            const int role = (r >= base1) ? 1 : 0;
#pragma unroll
            for (int n = 0; n < 4; n++) {
                const int col = bcol * 256 + (wc << 6) + (n << 4) + fr;
                float v = acc[m][n][j] + bias[col];
                if (mode == 1) v += rolerows[(size_t)role * N + col];
                v = v > 0.f ? v : 0.f;
                C[(size_t)r * N + col] = f2bf(v);
            }
        }
    }
}

// ---------------- final: head2 + tanh + gaussian logprob, wave per slot ----------------
__global__ __launch_bounds__(256) void head_final(
    const ushort* __restrict__ z,       // [slot][512] bf16 (own-role z)
    const float* __restrict__ actions,  // [T][8]
    const int* __restrict__ slot2tok, const int* __restrict__ scal,
    const ushort* __restrict__ hW2t,    // [2][8][512] bf16
    const float* __restrict__ hb2,      // [2][8]
    const float* __restrict__ log_stds, // [2][8]
    float* __restrict__ out) {
    const int lane = threadIdx.x & 63;
    const int s = blockIdx.x * (blockDim.x >> 6) + (threadIdx.x >> 6);
    const int c0 = scal[0], base1 = scal[4], mact = scal[5];
    if (s >= mact) return;
    if (s >= c0 && s < base1) return;  // pad gap
    const int r = (s >= base1) ? 1 : 0;
    const int t = slot2tok[s];

    const ushort* zp = z + (size_t)s * 512;
    uint4 zr = ((const uint4*)zp)[lane];
    unsigned zz[4] = {zr.x, zr.y, zr.z, zr.w};
    float zv[8];
#pragma unroll
    for (int i = 0; i < 4; i++) {
        zv[2 * i]     = bf2f((ushort)(zz[i] & 0xffffu));
        zv[2 * i + 1] = bf2f((ushort)(zz[i] >> 16));
    }
    float dk[8];
#pragma unroll
    for (int k = 0; k < 8; k++) {
        const ushort* wp = hW2t + r * 4096 + k * 512;
        uint4 wv = ((const uint4*)wp)[lane];
        unsigned ww[4] = {wv.x, wv.y, wv.z, wv.w};
        float sacc = 0.f;
#pragma unroll
        for (int i = 0; i < 4; i++) {
            sacc += zv[2 * i]     * bf2f((ushort)(ww[i] & 0xffffu));
            sacc += zv[2 * i + 1] * bf2f((ushort)(ww[i] >> 16));
        }
        dk[k] = sacc;
    }
#pragma unroll
    for (int off = 32; off >= 1; off >>= 1) {
#pragma unroll
        for (int k = 0; k < 8; k++) dk[k] += __shfl_xor(dk[k], off, 64);
    }
    if (lane == 0) {
        float lp = 0.f;
#pragma unroll
        for (int k = 0; k < 8; k++) {
            float mean = tanhf(dk[k] + hb2[r * 8 + k]);
            float ls = log_stds[r * 8 + k];
            float diff = (actions[(size_t)t * 8 + k] - mean) * expf(-ls);
            lp += -0.5f * diff * diff - ls - 0.5f * LOG_2PI_F;
        }
        out[t] = lp;
    }
}

extern "C" void kernel_launch(void* const* d_in, const int* in_sizes, int n_in,
                              void* d_out, int out_size, void* d_ws, size_t ws_size,
                              hipStream_t stream) {
    const float* obs      = (const float*)d_in[0];
    const int*   role_ids = (const int*)d_in[1];
    const float* actions  = (const float*)d_in[2];
    const float* W0       = (const float*)d_in[3];
    const float* b0       = (const float*)d_in[4];
    const float* W1       = (const float*)d_in[5];
    const float* b1       = (const float*)d_in[6];
    const float* W2       = (const float*)d_in[7];
    const float* b2       = (const float*)d_in[8];
    const float* hW1      = (const float*)d_in[9];
    const float* hb1      = (const float*)d_in[10];
    const float* hW2      = (const float*)d_in[11];
    const float* hb2      = (const float*)d_in[12];
    const float* log_stds = (const float*)d_in[13];
    float* out = (float*)d_out;

    const int T = 32768, H = 1024, OB = 128, H2 = 512;

    char* ws = (char*)d_ws;
    int*    scal = (int*)ws;    ws += 256;
    int* slot2tok = (int*)ws;   ws += (size_t)T * 4;            // 128 KB
    ushort* obsb = (ushort*)ws; ws += (size_t)T * OB * 2;       // 8 MB
    ushort* W0t  = (ushort*)ws; ws += (size_t)H * OB * 2;       // 256 KB
    ushort* W1t  = (ushort*)ws; ws += (size_t)H * H * 2;        // 2 MB
    ushort* W2t  = (ushort*)ws; ws += (size_t)H * H * 2;        // 2 MB
    ushort* hW1t = (ushort*)ws; ws += (size_t)H * H * 2;        // 2 MB (both roles)
    ushort* hW2t = (ushort*)ws; ws += (size_t)2 * 8 * H2 * 2;   // 16 KB
    ushort* bufA = (ushort*)ws; ws += (size_t)T * H * 2;        // 64 MB (h0, then h2)
    ushort* bufB = (ushort*)ws;                                 // 64 MB (h1, then z)

    // fused prep: compaction + obs gather + prey-out zero + all weight transposes
    prep_all<<<3360, 256, 0, stream>>>(obs, role_ids, W0, W1, W2, hW1, hW2,
                                       obsb, W0t, W1t, W2t, hW1t, hW2t,
                                       slot2tok, scal, out);

    // GEMMs over compacted rows (blocks past mpad early-exit); 128x256 tiles
    const int gridH = (T / 128) * (H / 256);   // 1024
    const int gridZ = (T / 128) * (H2 / 256);  // 512
    gemm_bias_relu<<<gridH, 512, 0, stream>>>(obsb, W0t, b0, bufA, H, OB, scal, W0 + 128 * H, 1);
    gemm_bias_relu<<<gridH, 512, 0, stream>>>(bufA, W1t, b1, bufB, H, H, scal, nullptr, 0);
    gemm_bias_relu<<<gridH, 512, 0, stream>>>(bufB, W2t, b2, bufA, H, H, scal, nullptr, 0);
    gemm_bias_relu<<<gridZ, 512, 0, stream>>>(bufA, hW1t, hb1, bufB, H2, H, scal, nullptr, 2);

    head_final<<<T / 4, 256, 0, stream>>>(bufB, actions, slot2tok, scal, hW2t, hb2, log_stds, out);
}